// Round 1
// baseline (2754.581 us; speedup 1.0000x reference)
//
#include <hip/hip_runtime.h>

#define CIN 32
#define COUT 32
#define DD 32
#define HH 48
#define WW 48
#define NTAP 27
#define SPATIAL (DD*HH*WW)   // 73728

// ---------------- Kernel 1: offset conv (81 output channels, pad=1) ----------
__global__ __launch_bounds__(256) void off_conv_kernel(
        const float* __restrict__ x,      // [32][32][48][48]
        const float* __restrict__ w_off,  // [81][32][3][3][3]
        float* __restrict__ offs)         // [81][SPATIAL]
{
    int idx = blockIdx.x * 256 + threadIdx.x;
    if (idx >= 81 * SPATIAL) return;
    int oc  = idx / SPATIAL;          // uniform within a block (SPATIAL%256==0)
    int pos = idx - oc * SPATIAL;
    int w = pos % WW;
    int h = (pos / WW) % HH;
    int d = pos / (WW * HH);

    const float* wq = w_off + oc * (CIN * NTAP);
    float acc = 0.f;
    for (int c = 0; c < CIN; ++c) {
        const float* xc = x + c * SPATIAL;
        const float* wc = wq + c * NTAP;
        #pragma unroll
        for (int kd = 0; kd < 3; ++kd) {
            int zd = d + kd - 1;
            if (zd < 0 || zd >= DD) continue;
            #pragma unroll
            for (int kh = 0; kh < 3; ++kh) {
                int zh = h + kh - 1;
                if (zh < 0 || zh >= HH) continue;
                #pragma unroll
                for (int kw = 0; kw < 3; ++kw) {
                    int zw = w + kw - 1;
                    if (zw < 0 || zw >= WW) continue;
                    acc = fmaf(xc[(zd * HH + zh) * WW + zw],
                               wc[kd * 9 + kh * 3 + kw], acc);
                }
            }
        }
    }
    offs[idx] = acc;
}

// -------- Kernel 2: fused deformable gather + trilinear + channel contraction
__global__ __launch_bounds__(256) void deform_kernel(
        const float* __restrict__ x,      // [32][32][48][48]
        const float* __restrict__ offs,   // [81][SPATIAL]
        const float* __restrict__ w_def,  // [32][32][27]
        float* __restrict__ out)          // [32][SPATIAL]
{
    int pos = blockIdx.x * 256 + threadIdx.x;
    if (pos >= SPATIAL) return;
    int w = pos % WW;
    int h = (pos / WW) % HH;
    int d = pos / (WW * HH);

    const float Dp1 = (float)(DD + 1);   // Dp-1 = 33
    const float Hp1 = (float)(HH + 1);   // 49
    const float Wp1 = (float)(WW + 1);   // 49

    float out_acc[COUT];
    #pragma unroll
    for (int o = 0; o < COUT; ++o) out_acc[o] = 0.f;

    for (int n = 0; n < NTAP; ++n) {
        float od = offs[(0 * NTAP + n) * SPATIAL + pos];
        float oh = offs[(1 * NTAP + n) * SPATIAL + pos];
        float ow = offs[(2 * NTAP + n) * SPATIAL + pos];
        float rd = (float)(n / 9) - 1.f;
        float rh = (float)((n / 3) % 3) - 1.f;
        float rw = (float)(n % 3) - 1.f;

        float pd = (float)(d + 1) + rd + od;
        float ph = (float)(h + 1) + rh + oh;
        float pw = (float)(w + 1) + rw + ow;

        float fd = floorf(pd), fh = floorf(ph), fw = floorf(pw);
        float qd0 = fminf(fmaxf(fd,       0.f), Dp1);
        float qd1 = fminf(fmaxf(fd + 1.f, 0.f), Dp1);
        float qh0 = fminf(fmaxf(fh,       0.f), Hp1);
        float qh1 = fminf(fmaxf(fh + 1.f, 0.f), Hp1);
        float qw0 = fminf(fmaxf(fw,       0.f), Wp1);
        float qw1 = fminf(fmaxf(fw + 1.f, 0.f), Wp1);
        pd = fminf(fmaxf(pd, 0.f), Dp1);
        ph = fminf(fmaxf(ph, 0.f), Hp1);
        pw = fminf(fmaxf(pw, 0.f), Wp1);

        float gds[2] = { 1.f + (qd0 - pd), 1.f - (qd1 - pd) };
        float ghs[2] = { 1.f + (qh0 - ph), 1.f - (qh1 - ph) };
        float gws[2] = { 1.f + (qw0 - pw), 1.f - (qw1 - pw) };
        int   ids[2] = { (int)qd0, (int)qd1 };
        int   ihs[2] = { (int)qh0, (int)qh1 };
        int   iws[2] = { (int)qw0, (int)qw1 };

        float xoff[CIN];
        #pragma unroll
        for (int c = 0; c < CIN; ++c) xoff[c] = 0.f;

        #pragma unroll
        for (int a = 0; a < 2; ++a) {
            #pragma unroll
            for (int b = 0; b < 2; ++b) {
                #pragma unroll
                for (int e = 0; e < 2; ++e) {
                    int zd = ids[a], zh = ihs[b], zw = iws[e];
                    float g = gds[a] * ghs[b] * gws[e];
                    // padded coords: valid real data is 1..D (pad ring is zero)
                    bool valid = (zd >= 1) & (zd <= DD) & (zh >= 1) & (zh <= HH)
                               & (zw >= 1) & (zw <= WW);
                    int base = valid ? (((zd - 1) * HH + (zh - 1)) * WW + (zw - 1)) : 0;
                    const float* xb = x + base;
                    #pragma unroll
                    for (int c = 0; c < CIN; ++c) {
                        float v = valid ? xb[c * SPATIAL] : 0.f;
                        xoff[c] = fmaf(g, v, xoff[c]);
                    }
                }
            }
        }

        const float* wd = w_def + n;   // w_def[(o*CIN+c)*NTAP + n]
        #pragma unroll
        for (int o = 0; o < COUT; ++o) {
            #pragma unroll
            for (int c = 0; c < CIN; ++c) {
                out_acc[o] = fmaf(xoff[c], wd[(o * CIN + c) * NTAP], out_acc[o]);
            }
        }
    }

    #pragma unroll
    for (int o = 0; o < COUT; ++o)
        out[o * SPATIAL + pos] = out_acc[o];
}

extern "C" void kernel_launch(void* const* d_in, const int* in_sizes, int n_in,
                              void* d_out, int out_size, void* d_ws, size_t ws_size,
                              hipStream_t stream)
{
    const float* x     = (const float*)d_in[0];
    const float* w_off = (const float*)d_in[1];
    const float* w_def = (const float*)d_in[2];
    float* out  = (float*)d_out;
    float* offs = (float*)d_ws;   // 81*73728 floats = 23.9 MB

    int conv_threads = 81 * SPATIAL;
    off_conv_kernel<<<(conv_threads + 255) / 256, 256, 0, stream>>>(x, w_off, offs);
    deform_kernel<<<(SPATIAL + 255) / 256, 256, 0, stream>>>(x, offs, w_def, out);
}

// Round 2
// 948.672 us; speedup vs baseline: 2.9036x; 2.9036x over previous
//
#include <hip/hip_runtime.h>

#define CIN 32
#define COUT 32
#define DD 32
#define HH 48
#define WW 48
#define NTAP 27
#define SPATIAL (DD*HH*WW)   // 73728

// conv tiling
#define OCG 27               // output channels per thread (81 = 3*27)
#define CCH 8                // input-channel chunk staged in LDS
#define TD 4
#define TH 8
#define TW 8
#define XT_D 6               // halo tile = (TD+2, TH+2, TW+2)
#define XT_H 10
#define XT_W 10
#define XT_SZ (XT_D*XT_H*XT_W)   // 600

// deform tap split
#define TAPG 3               // taps per block (27 = 9 groups * 3)

// ---------------------------------------------------------------- zero output
__global__ __launch_bounds__(256) void zero_out_kernel(float* __restrict__ out, int n)
{
    int i = blockIdx.x * 256 + threadIdx.x;
    if (i < n) out[i] = 0.f;
}

// ------------------------------------------------- Kernel 1: offset conv 3^3
// grid = (288 tiles, 3 axis-groups); thread computes 27 ocs for one position.
__global__ __launch_bounds__(256) void off_conv2(
        const float* __restrict__ x,      // [32][32][48][48]
        const float* __restrict__ w_off,  // [81][32][3][3][3]
        float* __restrict__ offs)         // [81][SPATIAL]
{
    __shared__ float xt[CCH * XT_SZ];     // 4800 f32 = 19.2 KB

    const int tile = blockIdx.x;          // 8*6*6 = 288
    const int ocg  = blockIdx.y;          // 0..2
    const int td = tile / 36, th = (tile / 6) % 6, twi = tile % 6;
    const int d0 = td * TD, h0 = th * TH, w0 = twi * TW;
    const int tid = threadIdx.x;
    const int lw = tid % TW, lh = (tid / TW) % TH, ld = tid / (TW * TH);

    float acc[OCG];
    #pragma unroll
    for (int i = 0; i < OCG; ++i) acc[i] = 0.f;

    for (int cc = 0; cc < CIN; cc += CCH) {
        __syncthreads();
        for (int idx = tid; idx < CCH * XT_SZ; idx += 256) {
            int zw = idx % XT_W;
            int zh = (idx / XT_W) % XT_H;
            int zd = (idx / (XT_W * XT_H)) % XT_D;
            int c  = idx / XT_SZ;
            int gd = d0 - 1 + zd, gh = h0 - 1 + zh, gw = w0 - 1 + zw;
            float v = 0.f;
            if (gd >= 0 && gd < DD && gh >= 0 && gh < HH && gw >= 0 && gw < WW)
                v = x[((cc + c) * DD + gd) * (HH * WW) + gh * WW + gw];
            xt[idx] = v;
        }
        __syncthreads();

        for (int c8 = 0; c8 < CCH; ++c8) {
            // weights for this (c, all 27 taps, 27 ocs): block-uniform -> s_load
            const float* wb = w_off + ((size_t)(ocg * OCG) * CIN + (cc + c8)) * NTAP;
            const float* xc = &xt[c8 * XT_SZ];
            #pragma unroll
            for (int kd = 0; kd < 3; ++kd) {
                #pragma unroll
                for (int kh = 0; kh < 3; ++kh) {
                    const float* xr = &xc[((ld + kd) * XT_H + (lh + kh)) * XT_W + lw];
                    #pragma unroll
                    for (int kw = 0; kw < 3; ++kw) {
                        float xv = xr[kw];
                        int tap = (kd * 3 + kh) * 3 + kw;
                        #pragma unroll
                        for (int i = 0; i < OCG; ++i)
                            acc[i] = fmaf(xv, wb[i * (CIN * NTAP) + tap], acc[i]);
                    }
                }
            }
        }
    }

    const int d = d0 + ld, h = h0 + lh, w = w0 + lw;
    const int pos = (d * HH + h) * WW + w;
    #pragma unroll
    for (int i = 0; i < OCG; ++i)
        offs[(size_t)(ocg * OCG + i) * SPATIAL + pos] = acc[i];
}

// ---------------- Kernel 2: deformable gather + trilinear + contraction
// grid = (288 pos-blocks, 9 tap-groups); each block does 3 taps, atomic-adds out.
__global__ __launch_bounds__(256) void deform2(
        const float* __restrict__ x,      // [32][32][48][48]
        const float* __restrict__ offs,   // [81][SPATIAL]
        const float* __restrict__ w_def,  // [32][32][27]
        float* __restrict__ out)          // [32][SPATIAL]
{
    __shared__ float wt[TAPG * CIN * COUT];   // [nl][c][o] = 3072 f32 = 12 KB

    const int tid = threadIdx.x;
    const int ng  = blockIdx.y;               // tap group 0..8
    const int pos = blockIdx.x * 256 + tid;
    const int w = pos % WW, h = (pos / WW) % HH, d = pos / (WW * HH);

    // stage weight slices for our 3 taps: wt[nl][c][o] = w_def[o][c][n]
    #pragma unroll
    for (int k = 0; k < 12; ++k) {
        int j  = tid + k * 256;               // 0..3071
        int nl = j >> 10;
        int rem = j & 1023;
        int c = rem >> 5, o = rem & 31;
        wt[j] = w_def[((size_t)o * CIN + c) * NTAP + ng * TAPG + nl];
    }
    __syncthreads();

    const float Dp1 = (float)(DD + 1);
    const float Hp1 = (float)(HH + 1);
    const float Wp1 = (float)(WW + 1);

    float oacc[COUT];
    #pragma unroll
    for (int o = 0; o < COUT; ++o) oacc[o] = 0.f;

    for (int nl = 0; nl < TAPG; ++nl) {
        const int n = ng * TAPG + nl;
        float od = offs[(size_t)(0 * NTAP + n) * SPATIAL + pos];
        float oh = offs[(size_t)(1 * NTAP + n) * SPATIAL + pos];
        float ow = offs[(size_t)(2 * NTAP + n) * SPATIAL + pos];
        float rd = (float)(n / 9) - 1.f;
        float rh = (float)((n / 3) % 3) - 1.f;
        float rw = (float)(n % 3) - 1.f;

        float pd = (float)(d + 1) + rd + od;
        float ph = (float)(h + 1) + rh + oh;
        float pw = (float)(w + 1) + rw + ow;

        float fd = floorf(pd), fh = floorf(ph), fw = floorf(pw);
        float qd0 = fminf(fmaxf(fd,       0.f), Dp1);
        float qd1 = fminf(fmaxf(fd + 1.f, 0.f), Dp1);
        float qh0 = fminf(fmaxf(fh,       0.f), Hp1);
        float qh1 = fminf(fmaxf(fh + 1.f, 0.f), Hp1);
        float qw0 = fminf(fmaxf(fw,       0.f), Wp1);
        float qw1 = fminf(fmaxf(fw + 1.f, 0.f), Wp1);
        pd = fminf(fmaxf(pd, 0.f), Dp1);
        ph = fminf(fmaxf(ph, 0.f), Hp1);
        pw = fminf(fmaxf(pw, 0.f), Wp1);

        float gds[2] = { 1.f + (qd0 - pd), 1.f - (qd1 - pd) };
        float ghs[2] = { 1.f + (qh0 - ph), 1.f - (qh1 - ph) };
        float gws[2] = { 1.f + (qw0 - pw), 1.f - (qw1 - pw) };
        int   ids[2] = { (int)qd0, (int)qd1 };
        int   ihs[2] = { (int)qh0, (int)qh1 };
        int   iws[2] = { (int)qw0, (int)qw1 };

        float xoff[CIN];
        #pragma unroll
        for (int c = 0; c < CIN; ++c) xoff[c] = 0.f;

        #pragma unroll
        for (int a = 0; a < 2; ++a) {
            #pragma unroll
            for (int b = 0; b < 2; ++b) {
                #pragma unroll
                for (int e = 0; e < 2; ++e) {
                    int zd = ids[a], zh = ihs[b], zw = iws[e];
                    float g = gds[a] * ghs[b] * gws[e];
                    bool valid = (zd >= 1) & (zd <= DD) & (zh >= 1) & (zh <= HH)
                               & (zw >= 1) & (zw <= WW);
                    int base = valid ? (((zd - 1) * HH + (zh - 1)) * WW + (zw - 1)) : 0;
                    const float* xb = x + base;
                    #pragma unroll
                    for (int c = 0; c < CIN; ++c) {
                        float v = valid ? xb[(size_t)c * SPATIAL] : 0.f;
                        xoff[c] = fmaf(g, v, xoff[c]);
                    }
                }
            }
        }

        const float* wrow = &wt[nl * (CIN * COUT)];
        #pragma unroll 4
        for (int c = 0; c < CIN; ++c) {
            float xv = xoff[c];
            const float4* wr = (const float4*)&wrow[c * COUT];
            #pragma unroll
            for (int o4 = 0; o4 < 8; ++o4) {
                float4 w4 = wr[o4];
                oacc[4 * o4 + 0] = fmaf(xv, w4.x, oacc[4 * o4 + 0]);
                oacc[4 * o4 + 1] = fmaf(xv, w4.y, oacc[4 * o4 + 1]);
                oacc[4 * o4 + 2] = fmaf(xv, w4.z, oacc[4 * o4 + 2]);
                oacc[4 * o4 + 3] = fmaf(xv, w4.w, oacc[4 * o4 + 3]);
            }
        }
    }

    #pragma unroll
    for (int o = 0; o < COUT; ++o)
        atomicAdd(&out[(size_t)o * SPATIAL + pos], oacc[o]);
}

// ----------------------------------------------------------------------------
extern "C" void kernel_launch(void* const* d_in, const int* in_sizes, int n_in,
                              void* d_out, int out_size, void* d_ws, size_t ws_size,
                              hipStream_t stream)
{
    const float* x     = (const float*)d_in[0];
    const float* w_off = (const float*)d_in[1];
    const float* w_def = (const float*)d_in[2];
    float* out  = (float*)d_out;
    float* offs = (float*)d_ws;   // 81*73728 f32 = 23.9 MB

    int outn = COUT * SPATIAL;
    zero_out_kernel<<<(outn + 255) / 256, 256, 0, stream>>>(out, outn);
    off_conv2<<<dim3(288, 3), 256, 0, stream>>>(x, w_off, offs);
    deform2<<<dim3(288, 9), 256, 0, stream>>>(x, offs, w_def, out);
}